// Round 1
// baseline (1268.562 us; speedup 1.0000x reference)
//
#include <hip/hip_runtime.h>

#define KTAPS 9
#define DIL 6
#define BN_EPS 1e-5f
#define BB 8
#define CIN 256
#define COUT 256
#define NPTS 8192
#define TN 64
#define CC 64

// ---------------------------------------------------------------- tap weights
__global__ __launch_bounds__(256)
void compute_g(const float* __restrict__ coords, const float* __restrict__ rot,
               const float* __restrict__ dist, float* __restrict__ g) {
  int idx = blockIdx.x * blockDim.x + threadIdx.x;   // b*NPTS + n
  if (idx >= BB * NPTS) return;
  int b = idx >> 13;           // /NPTS
  int n = idx & (NPTS - 1);
  const float* cb = coords + (size_t)b * 3 * NPTS;
  const float* rb = rot + (size_t)b * 3 * NPTS;
  const float* db = dist + (size_t)b * NPTS;
  float c0x = cb[n], c0y = cb[NPTS + n], c0z = cb[2 * NPTS + n];
  float r0x = rb[n], r0y = rb[NPTS + n], r0z = rb[2 * NPTS + n];
  float d0 = db[n];
  float r0n = r0x * r0x + r0y * r0y + r0z * r0z;
  for (int k = 0; k < KTAPS; ++k) {
    int j = n + (k - KTAPS / 2) * DIL;
    float gv = 0.f;
    if (j >= 0 && j < NPTS) {
      float dcx = c0x - cb[j], dcy = c0y - cb[NPTS + j], dcz = c0z - cb[2 * NPTS + j];
      float dc = dcx * dcx + dcy * dcy + dcz * dcz;
      float dd = d0 - db[j];
      dd *= dd;
      float gauss = expf(-(dc + dd) * 0.5f);   // sigma = 1
      float rjx = rb[j], rjy = rb[NPTS + j], rjz = rb[2 * NPTS + j];
      float num = r0x * rjx + r0y * rjy + r0z * rjz;
      float den = sqrtf(r0n * (rjx * rjx + rjy * rjy + rjz * rjz)) + 1e-8f;
      gv = gauss * fabsf(num / den);
    }
    g[((size_t)b * KTAPS + k) * NPTS + n] = gv;
  }
}

// ---------------------------------------------------------------- W transpose
// Wt[k][c][o] = W[o][c][k]
__global__ __launch_bounds__(256)
void transpose_w(const float* __restrict__ W, float* __restrict__ Wt) {
  int idx = blockIdx.x * blockDim.x + threadIdx.x;
  if (idx >= COUT * CIN * KTAPS) return;
  int o = idx & (COUT - 1);
  int c = (idx >> 8) & (CIN - 1);
  int k = idx >> 16;
  Wt[idx] = W[((size_t)o * CIN + c) * KTAPS + k];
}

// ---------------------------------------------------------------- conv + bias + BN partials
__global__ __launch_bounds__(256)
void conv_kernel(const float* __restrict__ x, const float* __restrict__ g,
                 const float* __restrict__ Wt, const float* __restrict__ bias,
                 float* __restrict__ out,
                 float* __restrict__ sums1, float* __restrict__ sums2) {
  __shared__ float xg[CC][TN];          // 16 KB, reused for output transpose
  __shared__ float red[2][COUT][2];     // 4 KB

  int tid = threadIdx.x;
  int b = blockIdx.y;
  int n0 = blockIdx.x * TN;
  int opair = tid & 127;                // o and o+128
  int nh = tid >> 7;                    // n half: 0/1
  int nb = nh * 32;

  float acc0[32], acc1[32];
#pragma unroll
  for (int i = 0; i < 32; ++i) { acc0[i] = 0.f; acc1[i] = 0.f; }

  int sn = tid & 63;                    // staging n
  int sc = tid >> 6;                    // staging c phase 0..3
  const float* xb = x + (size_t)b * CIN * NPTS;

  for (int k = 0; k < KTAPS; ++k) {
    int sk = (k - KTAPS / 2) * DIL;
    int jn = n0 + sn + sk;
    bool inr = (jn >= 0) && (jn < NPTS);
    float gk = g[((size_t)b * KTAPS + k) * NPTS + n0 + sn];
    const float* WtK = Wt + (size_t)k * CIN * COUT;
    for (int c0 = 0; c0 < CIN; c0 += CC) {
      __syncthreads();
#pragma unroll
      for (int i = 0; i < CC / 4; ++i) {
        int c = sc + 4 * i;
        float v = 0.f;
        if (inr) v = xb[(size_t)(c0 + c) * NPTS + jn] * gk;
        xg[c][sn] = v;
      }
      __syncthreads();
      const float* Wp = WtK + (size_t)c0 * COUT + opair;
      for (int c = 0; c < CC; ++c) {
        float w0 = Wp[c * COUT];
        float w1 = Wp[c * COUT + 128];
#pragma unroll
        for (int n = 0; n < 32; ++n) {
          float xv = xg[c][nb + n];
          acc0[n] = fmaf(w0, xv, acc0[n]);
          acc1[n] = fmaf(w1, xv, acc1[n]);
        }
      }
    }
  }

  // bias + per-channel partial stats
  float bv0 = bias[opair], bv1 = bias[opair + 128];
  float s1_0 = 0.f, s2_0 = 0.f, s1_1 = 0.f, s2_1 = 0.f;
#pragma unroll
  for (int n = 0; n < 32; ++n) {
    acc0[n] += bv0; acc1[n] += bv1;
    s1_0 += acc0[n]; s2_0 += acc0[n] * acc0[n];
    s1_1 += acc1[n]; s2_1 += acc1[n] * acc1[n];
  }
  red[0][opair][nh] = s1_0; red[0][opair + 128][nh] = s1_1;
  red[1][opair][nh] = s2_0; red[1][opair + 128][nh] = s2_1;
  __syncthreads();
  {
    int o = tid;
    atomicAdd(&sums1[o], red[0][o][0] + red[0][o][1]);
    atomicAdd(&sums2[o], red[1][o][0] + red[1][o][1]);
  }

  // coalesced output via LDS transpose, 4 passes of 64 output channels
  float* outb = out + (size_t)b * COUT * NPTS + n0;
  for (int p = 0; p < 4; ++p) {
    __syncthreads();
    if (p < 2) {
      if ((opair >> 6) == p) {
        int ol = opair & 63;
#pragma unroll
        for (int n = 0; n < 32; ++n) xg[ol][nb + n] = acc0[n];
      }
    } else {
      if ((opair >> 6) == (p - 2)) {
        int ol = opair & 63;
#pragma unroll
        for (int n = 0; n < 32; ++n) xg[ol][nb + n] = acc1[n];
      }
    }
    __syncthreads();
#pragma unroll
    for (int i = 0; i < 16; ++i) {
      int row = (tid >> 6) + 4 * i;
      outb[(size_t)(p * 64 + row) * NPTS + sn] = xg[row][sn];
    }
  }
}

// ---------------------------------------------------------------- BN + ReLU
__global__ __launch_bounds__(256)
void bn_apply(float* __restrict__ out, const float* __restrict__ sums1,
              const float* __restrict__ sums2, const float* __restrict__ gamma,
              const float* __restrict__ beta) {
  int bo = blockIdx.x;                  // b*COUT + o
  int o = bo & (COUT - 1);
  const float inv = 1.f / (float)(BB * NPTS);
  float mean = sums1[o] * inv;
  float var = sums2[o] * inv - mean * mean;
  float scale = gamma[o] * rsqrtf(var + BN_EPS);
  float shift = beta[o] - mean * scale;
  float4* p = (float4*)(out + (size_t)bo * NPTS);
  for (int i = threadIdx.x; i < NPTS / 4; i += blockDim.x) {
    float4 v = p[i];
    v.x = fmaxf(fmaf(v.x, scale, shift), 0.f);
    v.y = fmaxf(fmaf(v.y, scale, shift), 0.f);
    v.z = fmaxf(fmaf(v.z, scale, shift), 0.f);
    v.w = fmaxf(fmaf(v.w, scale, shift), 0.f);
    p[i] = v;
  }
}

// ---------------------------------------------------------------- launch
extern "C" void kernel_launch(void* const* d_in, const int* in_sizes, int n_in,
                              void* d_out, int out_size, void* d_ws, size_t ws_size,
                              hipStream_t stream) {
  const float* x      = (const float*)d_in[0];  // [8,256,8192]
  const float* coords = (const float*)d_in[1];  // [8,3,8192]
  const float* rot    = (const float*)d_in[2];  // [8,3,8192]
  const float* dist   = (const float*)d_in[3];  // [8,8192]
  const float* W      = (const float*)d_in[4];  // [256,256,9]
  const float* bias   = (const float*)d_in[5];  // [256]
  const float* gamma  = (const float*)d_in[6];  // [256]
  const float* beta   = (const float*)d_in[7];  // [256]
  float* out = (float*)d_out;

  float* ws    = (float*)d_ws;
  float* sums1 = ws;                       // 256
  float* sums2 = ws + 256;                 // 256
  float* g     = ws + 512;                 // 8*9*8192 = 589824
  float* Wt    = g + (size_t)BB * KTAPS * NPTS;  // 589824

  hipMemsetAsync(sums1, 0, 512 * sizeof(float), stream);

  compute_g<<<(BB * NPTS + 255) / 256, 256, 0, stream>>>(coords, rot, dist, g);
  transpose_w<<<(COUT * CIN * KTAPS + 255) / 256, 256, 0, stream>>>(W, Wt);
  conv_kernel<<<dim3(NPTS / TN, BB), 256, 0, stream>>>(x, g, Wt, bias, out, sums1, sums2);
  bn_apply<<<BB * COUT, 256, 0, stream>>>(out, sums1, sums2, gamma, beta);
}

// Round 2
// 360.329 us; speedup vs baseline: 3.5206x; 3.5206x over previous
//
#include <hip/hip_runtime.h>

#define KTAPS 9
#define DIL 6
#define BN_EPS 1e-5f
#define BB 8
#define CIN 256
#define COUT 256
#define NPTS 8192
#define BN 64
#define NCHUNK 72   // 2304 / 32

typedef __attribute__((ext_vector_type(8))) short short8;
typedef __attribute__((ext_vector_type(4))) float f32x4;

__device__ __forceinline__ unsigned short f2bf(float f) {
  union { float f; unsigned u; } v; v.f = f;
  unsigned r = v.u + 0x7fffu + ((v.u >> 16) & 1u);   // round-to-nearest-even
  return (unsigned short)(r >> 16);
}

__device__ __forceinline__ void async16(const void* gp, void* lp) {
  __builtin_amdgcn_global_load_lds(
      (const __attribute__((address_space(1))) unsigned int*)gp,
      (__attribute__((address_space(3))) unsigned int*)lp, 16, 0, 0);
}

// ---------------------------------------------------------------- tap weights
__global__ __launch_bounds__(256)
void compute_g(const float* __restrict__ coords, const float* __restrict__ rot,
               const float* __restrict__ dist, float* __restrict__ g) {
  int idx = blockIdx.x * blockDim.x + threadIdx.x;   // b*NPTS + n
  if (idx >= BB * NPTS) return;
  int b = idx >> 13;
  int n = idx & (NPTS - 1);
  const float* cb = coords + (size_t)b * 3 * NPTS;
  const float* rb = rot + (size_t)b * 3 * NPTS;
  const float* db = dist + (size_t)b * NPTS;
  float c0x = cb[n], c0y = cb[NPTS + n], c0z = cb[2 * NPTS + n];
  float r0x = rb[n], r0y = rb[NPTS + n], r0z = rb[2 * NPTS + n];
  float d0 = db[n];
  float r0n = r0x * r0x + r0y * r0y + r0z * r0z;
  for (int k = 0; k < KTAPS; ++k) {
    int j = n + (k - KTAPS / 2) * DIL;
    float gv = 0.f;
    if (j >= 0 && j < NPTS) {
      float dcx = c0x - cb[j], dcy = c0y - cb[NPTS + j], dcz = c0z - cb[2 * NPTS + j];
      float dc = dcx * dcx + dcy * dcy + dcz * dcz;
      float dd = d0 - db[j];
      dd *= dd;
      float gauss = expf(-(dc + dd) * 0.5f);
      float rjx = rb[j], rjy = rb[NPTS + j], rjz = rb[2 * NPTS + j];
      float num = r0x * rjx + r0y * rjy + r0z * rjz;
      float den = sqrtf(r0n * (rjx * rjx + rjy * rjy + rjz * rjz)) + 1e-8f;
      gv = gauss * fabsf(num / den);
    }
    g[((size_t)b * KTAPS + k) * NPTS + n] = gv;
  }
}

// ---------------------------------------------------------------- pack W -> bf16, tile-blocked
// Wa[chunk][mi 0..255][kk 0..31], chunk = ktap*8 + c8; element = W[mi][c8*32+kk][ktap]
__global__ __launch_bounds__(256)
void pack_w(const float* __restrict__ W, short* __restrict__ Wa) {
  int idx = blockIdx.x * blockDim.x + threadIdx.x;
  if (idx >= NCHUNK * 8192) return;
  int kk = idx & 31;
  int mi = (idx >> 5) & 255;
  int chunk = idx >> 13;
  int ktap = chunk >> 3;
  int c = ((chunk & 7) << 5) + kk;
  Wa[idx] = (short)f2bf(W[(size_t)mi * (CIN * KTAPS) + c * KTAPS + ktap]);
}

// ---------------------------------------------------------------- MFMA conv + bias + BN partials
__global__ __launch_bounds__(256)
void conv_mfma(const float* __restrict__ x, const float* __restrict__ g,
               const short* __restrict__ Wa, const float* __restrict__ bias,
               float* __restrict__ out,
               float* __restrict__ sums1, float* __restrict__ sums2) {
  __shared__ short A_lds[256 * 32];      // [m][kk], 16 KB, unpadded (global_load_lds order)
  __shared__ short B_lds[BN * 40];       // [n][kk], stride 40 elems (80 B) kills write conflicts

  const int tid = threadIdx.x;
  const int b = blockIdx.y;
  const int n0 = blockIdx.x * BN;
  const int wave = tid >> 6;
  const int lane = tid & 63;
  const int col = lane & 15;
  const int quad = lane >> 4;

  f32x4 acc[4][4];
#pragma unroll
  for (int i = 0; i < 4; ++i)
#pragma unroll
    for (int j = 0; j < 4; ++j) acc[i][j] = (f32x4)0.f;

  const int sn = tid & 63;     // staging n
  const int skg = tid >> 6;    // staging kk-group (8 rows each)
  const float* xb = x + (size_t)b * CIN * NPTS;

  for (int k = 0; k < KTAPS; ++k) {
    const int off = (k - KTAPS / 2) * DIL;
    const float gval = g[((size_t)b * KTAPS + k) * NPTS + n0 + sn];
    const int jn = n0 + sn + off;
    const bool inr = (jn >= 0) && (jn < NPTS);
    const float* xcol = xb + jn;

    for (int c8 = 0; c8 < 8; ++c8) {
      const int chunk = k * 8 + c8;
      // ---- stage A: 16 KB via global_load_lds width-16 (4 insts/thread)
      const short* wsrc = Wa + (size_t)chunk * 8192 + tid * 8;
#pragma unroll
      for (int t = 0; t < 4; ++t)
        async16(wsrc + t * 2048, &A_lds[tid * 8 + t * 2048]);

      // ---- stage B: xg[kk][n] computed in-flight, written transposed [n][kk]
      const int cb = c8 * 32 + skg * 8;
      float xv[8];
#pragma unroll
      for (int jj = 0; jj < 8; ++jj)
        xv[jj] = inr ? xcol[(size_t)(cb + jj) * NPTS] : 0.f;
      short8 pk;
#pragma unroll
      for (int jj = 0; jj < 8; ++jj) pk[jj] = (short)f2bf(xv[jj] * gval);
      *(short8*)&B_lds[sn * 40 + skg * 8] = pk;

      __syncthreads();   // drains vmcnt (global_load_lds) + lgkm (ds_write)

      // ---- MFMA: wave covers m = wave*64..+63, n = 0..63
      short8 af[4];
#pragma unroll
      for (int i = 0; i < 4; ++i)
        af[i] = *(short8*)&A_lds[(wave * 64 + i * 16 + col) * 32 + quad * 8];
#pragma unroll
      for (int j = 0; j < 4; ++j) {
        short8 bfv = *(short8*)&B_lds[(j * 16 + col) * 40 + quad * 8];
#pragma unroll
        for (int i = 0; i < 4; ++i)
          acc[i][j] = __builtin_amdgcn_mfma_f32_16x16x32_bf16(af[i], bfv, acc[i][j], 0, 0, 0);
      }
      __syncthreads();
    }
  }

  // ---- epilogue: bias, BN partial sums, store
  const int obase = wave * 64;
  float* outp = out + (size_t)b * COUT * NPTS + n0;
#pragma unroll
  for (int i = 0; i < 4; ++i) {
    const int o0 = obase + i * 16 + quad * 4;
    const float4 bv = *(const float4*)&bias[o0];
#pragma unroll
    for (int j = 0; j < 4; ++j) {
      acc[i][j][0] += bv.x; acc[i][j][1] += bv.y;
      acc[i][j][2] += bv.z; acc[i][j][3] += bv.w;
    }
#pragma unroll
    for (int r = 0; r < 4; ++r) {
      float s1 = 0.f, s2 = 0.f;
#pragma unroll
      for (int j = 0; j < 4; ++j) {
        float v = acc[i][j][r];
        s1 += v; s2 += v * v;
      }
      s1 += __shfl_xor(s1, 1); s2 += __shfl_xor(s2, 1);
      s1 += __shfl_xor(s1, 2); s2 += __shfl_xor(s2, 2);
      s1 += __shfl_xor(s1, 4); s2 += __shfl_xor(s2, 4);
      s1 += __shfl_xor(s1, 8); s2 += __shfl_xor(s2, 8);
      if (col == 0) {
        atomicAdd(&sums1[o0 + r], s1);
        atomicAdd(&sums2[o0 + r], s2);
      }
    }
#pragma unroll
    for (int j = 0; j < 4; ++j)
#pragma unroll
      for (int r = 0; r < 4; ++r)
        outp[(size_t)(o0 + r) * NPTS + j * 16 + col] = acc[i][j][r];
  }
}

// ---------------------------------------------------------------- BN + ReLU
__global__ __launch_bounds__(256)
void bn_apply(float* __restrict__ out, const float* __restrict__ sums1,
              const float* __restrict__ sums2, const float* __restrict__ gamma,
              const float* __restrict__ beta) {
  int bo = blockIdx.x;
  int o = bo & (COUT - 1);
  const float inv = 1.f / (float)(BB * NPTS);
  float mean = sums1[o] * inv;
  float var = sums2[o] * inv - mean * mean;
  float scale = gamma[o] * rsqrtf(var + BN_EPS);
  float shift = beta[o] - mean * scale;
  float4* p = (float4*)(out + (size_t)bo * NPTS);
  for (int i = threadIdx.x; i < NPTS / 4; i += blockDim.x) {
    float4 v = p[i];
    v.x = fmaxf(fmaf(v.x, scale, shift), 0.f);
    v.y = fmaxf(fmaf(v.y, scale, shift), 0.f);
    v.z = fmaxf(fmaf(v.z, scale, shift), 0.f);
    v.w = fmaxf(fmaf(v.w, scale, shift), 0.f);
    p[i] = v;
  }
}

// ---------------------------------------------------------------- launch
extern "C" void kernel_launch(void* const* d_in, const int* in_sizes, int n_in,
                              void* d_out, int out_size, void* d_ws, size_t ws_size,
                              hipStream_t stream) {
  const float* x      = (const float*)d_in[0];
  const float* coords = (const float*)d_in[1];
  const float* rot    = (const float*)d_in[2];
  const float* dist   = (const float*)d_in[3];
  const float* W      = (const float*)d_in[4];
  const float* bias   = (const float*)d_in[5];
  const float* gamma  = (const float*)d_in[6];
  const float* beta   = (const float*)d_in[7];
  float* out = (float*)d_out;

  float* ws    = (float*)d_ws;
  float* sums1 = ws;                                  // 256
  float* sums2 = ws + 256;                            // 256
  float* g     = ws + 512;                            // 8*9*8192 floats
  short* Wa    = (short*)(g + (size_t)BB * KTAPS * NPTS);  // 72*8192 bf16

  hipMemsetAsync(sums1, 0, 512 * sizeof(float), stream);

  compute_g<<<(BB * NPTS + 255) / 256, 256, 0, stream>>>(coords, rot, dist, g);
  pack_w<<<(NCHUNK * 8192 + 255) / 256, 256, 0, stream>>>(W, Wa);
  conv_mfma<<<dim3(NPTS / BN, BB), 256, 0, stream>>>(x, g, Wa, bias, out, sums1, sums2);
  bn_apply<<<BB * COUT, 256, 0, stream>>>(out, sums1, sums2, gamma, beta);
}

// Round 3
// 292.930 us; speedup vs baseline: 4.3306x; 1.2301x over previous
//
#include <hip/hip_runtime.h>

#define KTAPS 9
#define DIL 6
#define BN_EPS 1e-5f
#define BB 8
#define CIN 256
#define COUT 256
#define NPTS 8192
#define BN 128
#define NCHUNK 72   // 2304 / 32

typedef __attribute__((ext_vector_type(8))) short short8;
typedef __attribute__((ext_vector_type(4))) float f32x4;

__device__ __forceinline__ unsigned short f2bf(float f) {
  union { float f; unsigned u; } v; v.f = f;
  unsigned r = v.u + 0x7fffu + ((v.u >> 16) & 1u);   // RNE
  return (unsigned short)(r >> 16);
}

__device__ __forceinline__ void async16(const void* gp, void* lp) {
  __builtin_amdgcn_global_load_lds(
      (const __attribute__((address_space(1))) unsigned int*)gp,
      (__attribute__((address_space(3))) unsigned int*)lp, 16, 0, 0);
}

// ---------------------------------------------------------------- fused pre:
// blocks [0,2304): g, one tap per thread
// blocks [2304,4608): pack W -> bf16 tile-blocked
// block 4608: zero sums
__global__ __launch_bounds__(256)
void pre_kernel(const float* __restrict__ coords, const float* __restrict__ rot,
                const float* __restrict__ dist, const float* __restrict__ W,
                float* __restrict__ g, short* __restrict__ Wa,
                float* __restrict__ sums) {
  int bid = blockIdx.x;
  if (bid < 2304) {
    int gid = bid * 256 + threadIdx.x;     // index into g[b][k][n]
    int n = gid & (NPTS - 1);
    int bk = gid >> 13;
    int k = bk % KTAPS;
    int b = bk / KTAPS;
    const float* cb = coords + (size_t)b * 3 * NPTS;
    const float* rb = rot + (size_t)b * 3 * NPTS;
    const float* db = dist + (size_t)b * NPTS;
    int j = n + (k - KTAPS / 2) * DIL;
    float gv = 0.f;
    if (j >= 0 && j < NPTS) {
      float c0x = cb[n], c0y = cb[NPTS + n], c0z = cb[2 * NPTS + n];
      float r0x = rb[n], r0y = rb[NPTS + n], r0z = rb[2 * NPTS + n];
      float dcx = c0x - cb[j], dcy = c0y - cb[NPTS + j], dcz = c0z - cb[2 * NPTS + j];
      float dc = dcx * dcx + dcy * dcy + dcz * dcz;
      float dd = db[n] - db[j];
      dd *= dd;
      float gauss = expf(-(dc + dd) * 0.5f);
      float rjx = rb[j], rjy = rb[NPTS + j], rjz = rb[2 * NPTS + j];
      float num = r0x * rjx + r0y * rjy + r0z * rjz;
      float r0n = r0x * r0x + r0y * r0y + r0z * r0z;
      float den = sqrtf(r0n * (rjx * rjx + rjy * rjy + rjz * rjz)) + 1e-8f;
      gv = gauss * fabsf(num / den);
    }
    g[gid] = gv;
  } else if (bid < 4608) {
    int idx = (bid - 2304) * 256 + threadIdx.x;
    int kk = idx & 31;
    int mi = (idx >> 5) & 255;
    int chunk = idx >> 13;
    int ktap = chunk >> 3;
    int c = ((chunk & 7) << 5) + kk;
    Wa[idx] = (short)f2bf(W[(size_t)mi * (CIN * KTAPS) + c * KTAPS + ktap]);
  } else {
    if (threadIdx.x < 512) sums[threadIdx.x] = 0.f;
  }
}

// ---------------------------------------------------------------- MFMA conv, pipelined dbuf
__global__ __launch_bounds__(256, 2)
void conv_mfma(const float* __restrict__ x, const float* __restrict__ g,
               const short* __restrict__ Wa, const float* __restrict__ bias,
               float* __restrict__ out,
               float* __restrict__ sums1, float* __restrict__ sums2) {
  __shared__ short A_lds[2][256 * 32];   // 2 x 16 KB  [m][kk]
  __shared__ short B_lds[2][BN * 40];    // 2 x 10 KB  [n][kk], stride 40

  const int tid = threadIdx.x;
  const int b = blockIdx.y;
  const int n0 = blockIdx.x * BN;
  const int wave = tid >> 6;
  const int lane = tid & 63;
  const int col = lane & 15;
  const int quad = lane >> 4;

  const int sn = tid & 127;        // staging n (0..127)
  const int skg = (tid >> 7) * 16; // staging kk base (0 or 16)
  const float* xb = x + (size_t)b * CIN * NPTS;
  const float* gb = g + ((size_t)b * KTAPS) * NPTS + n0 + sn;

  f32x4 acc[4][8];
#pragma unroll
  for (int i = 0; i < 4; ++i)
#pragma unroll
    for (int j = 0; j < 8; ++j) acc[i][j] = (f32x4)0.f;

  float xv[16];
  float gval;

  // ---- prologue: stage chunk 0 into buf 0
  {
    const short* wsrc = Wa + tid * 8;
#pragma unroll
    for (int t = 0; t < 4; ++t)
      async16(wsrc + t * 2048, &A_lds[0][tid * 8 + t * 2048]);
    const int jn = n0 + sn + (0 - 4) * DIL;          // k=0
    const bool inr = (jn >= 0) && (jn < NPTS);
    const float* xcol = xb + (size_t)skg * NPTS + jn;
    gval = gb[0];
#pragma unroll
    for (int jj = 0; jj < 16; ++jj)
      xv[jj] = inr ? xcol[(size_t)jj * NPTS] : 0.f;
    short8 p0, p1;
#pragma unroll
    for (int jj = 0; jj < 8; ++jj) { p0[jj] = (short)f2bf(xv[jj] * gval); p1[jj] = (short)f2bf(xv[8 + jj] * gval); }
    *(short8*)&B_lds[0][sn * 40 + skg] = p0;
    *(short8*)&B_lds[0][sn * 40 + skg + 8] = p1;
  }
  __syncthreads();

  for (int i = 0; i < NCHUNK; ++i) {
    const int cur = i & 1;
    const int nxt = cur ^ 1;
    const bool more = (i + 1) < NCHUNK;

    // ---- prefetch chunk i+1: A via async DMA, x into registers
    if (more) {
      const int i1 = i + 1;
      const short* wsrc = Wa + (size_t)i1 * 8192 + tid * 8;
#pragma unroll
      for (int t = 0; t < 4; ++t)
        async16(wsrc + t * 2048, &A_lds[nxt][tid * 8 + t * 2048]);
      const int k1 = i1 >> 3;
      const int c81 = i1 & 7;
      const int jn = n0 + sn + (k1 - 4) * DIL;
      const bool inr = (jn >= 0) && (jn < NPTS);
      const float* xcol = xb + (size_t)(c81 * 32 + skg) * NPTS + jn;
      gval = gb[(size_t)k1 * NPTS];
#pragma unroll
      for (int jj = 0; jj < 16; ++jj)
        xv[jj] = inr ? xcol[(size_t)jj * NPTS] : 0.f;
    }

    // ---- MFMA on buf cur
    {
      short8 af[4];
#pragma unroll
      for (int m = 0; m < 4; ++m)
        af[m] = *(short8*)&A_lds[cur][(wave * 64 + m * 16 + col) * 32 + quad * 8];
#pragma unroll
      for (int j = 0; j < 8; ++j) {
        short8 bfv = *(short8*)&B_lds[cur][(j * 16 + col) * 40 + quad * 8];
#pragma unroll
        for (int m = 0; m < 4; ++m)
          acc[m][j] = __builtin_amdgcn_mfma_f32_16x16x32_bf16(af[m], bfv, acc[m][j], 0, 0, 0);
      }
    }

    // ---- convert + stage B for chunk i+1
    if (more) {
      short8 p0, p1;
#pragma unroll
      for (int jj = 0; jj < 8; ++jj) { p0[jj] = (short)f2bf(xv[jj] * gval); p1[jj] = (short)f2bf(xv[8 + jj] * gval); }
      *(short8*)&B_lds[nxt][sn * 40 + skg] = p0;
      *(short8*)&B_lds[nxt][sn * 40 + skg + 8] = p1;
    }
    __syncthreads();
  }

  // ---- epilogue: bias, BN partials, store
  const int obase = wave * 64;
  float* outp = out + (size_t)b * COUT * NPTS + n0;
#pragma unroll
  for (int m = 0; m < 4; ++m) {
    const int o0 = obase + m * 16 + quad * 4;
    const float4 bv = *(const float4*)&bias[o0];
#pragma unroll
    for (int j = 0; j < 8; ++j) {
      acc[m][j][0] += bv.x; acc[m][j][1] += bv.y;
      acc[m][j][2] += bv.z; acc[m][j][3] += bv.w;
    }
#pragma unroll
    for (int r = 0; r < 4; ++r) {
      float s1 = 0.f, s2 = 0.f;
#pragma unroll
      for (int j = 0; j < 8; ++j) {
        float v = acc[m][j][r];
        s1 += v; s2 += v * v;
      }
      s1 += __shfl_xor(s1, 1); s2 += __shfl_xor(s2, 1);
      s1 += __shfl_xor(s1, 2); s2 += __shfl_xor(s2, 2);
      s1 += __shfl_xor(s1, 4); s2 += __shfl_xor(s2, 4);
      s1 += __shfl_xor(s1, 8); s2 += __shfl_xor(s2, 8);
      if (col == 0) {
        atomicAdd(&sums1[o0 + r], s1);
        atomicAdd(&sums2[o0 + r], s2);
      }
#pragma unroll
      for (int j = 0; j < 8; ++j)
        outp[(size_t)(o0 + r) * NPTS + j * 16 + col] = acc[m][j][r];
    }
  }
}

// ---------------------------------------------------------------- BN + ReLU
__global__ __launch_bounds__(256)
void bn_apply(float* __restrict__ out, const float* __restrict__ sums1,
              const float* __restrict__ sums2, const float* __restrict__ gamma,
              const float* __restrict__ beta) {
  int bo = blockIdx.x;
  int o = bo & (COUT - 1);
  const float inv = 1.f / (float)(BB * NPTS);
  float mean = sums1[o] * inv;
  float var = sums2[o] * inv - mean * mean;
  float scale = gamma[o] * rsqrtf(var + BN_EPS);
  float shift = beta[o] - mean * scale;
  float4* p = (float4*)(out + (size_t)bo * NPTS);
  for (int i = threadIdx.x; i < NPTS / 4; i += blockDim.x) {
    float4 v = p[i];
    v.x = fmaxf(fmaf(v.x, scale, shift), 0.f);
    v.y = fmaxf(fmaf(v.y, scale, shift), 0.f);
    v.z = fmaxf(fmaf(v.z, scale, shift), 0.f);
    v.w = fmaxf(fmaf(v.w, scale, shift), 0.f);
    p[i] = v;
  }
}

// ---------------------------------------------------------------- launch
extern "C" void kernel_launch(void* const* d_in, const int* in_sizes, int n_in,
                              void* d_out, int out_size, void* d_ws, size_t ws_size,
                              hipStream_t stream) {
  const float* x      = (const float*)d_in[0];
  const float* coords = (const float*)d_in[1];
  const float* rot    = (const float*)d_in[2];
  const float* dist   = (const float*)d_in[3];
  const float* W      = (const float*)d_in[4];
  const float* bias   = (const float*)d_in[5];
  const float* gamma  = (const float*)d_in[6];
  const float* beta   = (const float*)d_in[7];
  float* out = (float*)d_out;

  float* ws    = (float*)d_ws;
  float* sums1 = ws;                                   // 256
  float* sums2 = ws + 256;                             // 256
  float* g     = ws + 512;                             // 8*9*8192 floats
  short* Wa    = (short*)(g + (size_t)BB * KTAPS * NPTS);  // 72*8192 bf16

  pre_kernel<<<4609, 256, 0, stream>>>(coords, rot, dist, W, g, Wa, sums1);
  conv_mfma<<<dim3(NPTS / BN, BB), 256, 0, stream>>>(x, g, Wa, bias, out, sums1, sums2);
  bn_apply<<<BB * COUT, 256, 0, stream>>>(out, sums1, sums2, gamma, beta);
}